// Round 1
// baseline (1284.036 us; speedup 1.0000x reference)
//
#include <hip/hip_runtime.h>

#define DD 64          // embedding dim
#define SS 20          // neighbors per node
#define NPB 64         // nodes per block
#define NPW 16         // nodes per wave
#define NB  4          // nodes batched per wave iteration

// One block = 256 threads = 4 waves. Each wave processes 16 nodes (4 batches of 4).
// LDS: WT[128][64] fp32, transposed + XOR-swizzled (word = k*64 + (j ^ (k&31)))
//      -> conflict-free writes (2-way) and conflict-free matmul reads (2-way).
//      X[4 waves][4 nodes][128] per-wave x = [self ; neigh_mean], broadcast-read as float4.
__global__ __launch_bounds__(256) void sage_kernel(
    const int*   __restrict__ nodes,
    const int*   __restrict__ nbrs,
    const float* __restrict__ table,
    const float* __restrict__ Ws,
    const float* __restrict__ bs,
    const float* __restrict__ Wn,
    const float* __restrict__ bn,
    float*       __restrict__ out,
    int N)
{
    __shared__ float WT[128 * 64];
    __shared__ float X[4][NB][128];

    const int tid  = threadIdx.x;
    const int lane = tid & 63;
    const int wid  = tid >> 6;

    // --- stage W transposed + swizzled into LDS (coalesced global reads) ---
    for (int i = tid; i < 64 * 64; i += 256) {
        const int j  = i >> 6;         // output dim
        const int k  = i & 63;         // input dim
        const int jj = j ^ (k & 31);   // swizzle
        WT[k * 64 + jj]        = Ws[i];   // W2[j][k] for k<64
        WT[(k + 64) * 64 + jj] = Wn[i];   // W2[j][64+k]
    }
    const float bias = bs[lane] + bn[lane];
    __syncthreads();

    const int base = blockIdx.x * NPB + wid * NPW;

    for (int it = 0; it < NPW / NB; ++it) {
        const int n0 = base + it * NB;

        // --- gather: self row + mean of 20 neighbor rows, per node ---
        #pragma unroll
        for (int u = 0; u < NB; ++u) {
            const int ni = n0 + u;
            float selfv = 0.f, agg = 0.f;
            if (ni < N) {
                const int idx = nodes[ni];
                selfv = table[idx * DD + lane];
                int nb = 0;
                if (lane < SS) nb = nbrs[ni * SS + lane];
                #pragma unroll
                for (int s = 0; s < SS; ++s) {
                    const int bi = __builtin_amdgcn_readlane(nb, s); // uniform -> SGPR base
                    agg += table[bi * DD + lane];                     // coalesced 256B row read
                }
                agg *= (1.0f / SS);
            }
            X[wid][u][lane]      = selfv;
            X[wid][u][DD + lane] = agg;
        }
        // X written & read by the same wave: in-order LDS, no barrier needed.

        // --- matmul: h[u][j=lane] = bias + sum_k X[u][k] * W2[j][k] ---
        float h[NB];
        #pragma unroll
        for (int u = 0; u < NB; ++u) h[u] = bias;

        #pragma unroll
        for (int k4 = 0; k4 < 32; ++k4) {
            const int k = k4 * 4;
            const float w0 = WT[(k + 0) * 64 + (lane ^ ((k + 0) & 31))];
            const float w1 = WT[(k + 1) * 64 + (lane ^ ((k + 1) & 31))];
            const float w2 = WT[(k + 2) * 64 + (lane ^ ((k + 2) & 31))];
            const float w3 = WT[(k + 3) * 64 + (lane ^ ((k + 3) & 31))];
            #pragma unroll
            for (int u = 0; u < NB; ++u) {
                const float4 xv = *(const float4*)&X[wid][u][k]; // broadcast ds_read_b128
                float hu = h[u];
                hu = fmaf(xv.x, w0, hu);
                hu = fmaf(xv.y, w1, hu);
                hu = fmaf(xv.z, w2, hu);
                hu = fmaf(xv.w, w3, hu);
                h[u] = hu;
            }
        }

        // --- epilogue: relu -> L2 normalize (eps=1e-12) -> store ---
        #pragma unroll
        for (int u = 0; u < NB; ++u) {
            const int ni = n0 + u;
            if (ni >= N) continue;   // wave-uniform branch
            const float v = fmaxf(h[u], 0.f);
            float ss2 = v * v;
            #pragma unroll
            for (int off = 32; off > 0; off >>= 1)
                ss2 += __shfl_xor(ss2, off, 64);
            const float nrm = fmaxf(sqrtf(ss2), 1e-12f);
            out[ni * DD + lane] = v / nrm;
        }
    }
}

extern "C" void kernel_launch(void* const* d_in, const int* in_sizes, int n_in,
                              void* d_out, int out_size, void* d_ws, size_t ws_size,
                              hipStream_t stream) {
    const int*   user_nodes = (const int*)  d_in[0];
    const int*   item_nodes = (const int*)  d_in[1];
    const int*   user_nbrs  = (const int*)  d_in[2];
    const int*   item_nbrs  = (const int*)  d_in[3];
    const float* user_table = (const float*)d_in[4];
    const float* item_table = (const float*)d_in[5];
    const float* Wsu = (const float*)d_in[6];
    const float* bsu = (const float*)d_in[7];
    const float* Wnu = (const float*)d_in[8];
    const float* bnu = (const float*)d_in[9];
    const float* Wsi = (const float*)d_in[10];
    const float* bsi = (const float*)d_in[11];
    const float* Wni = (const float*)d_in[12];
    const float* bni = (const float*)d_in[13];

    float* out = (float*)d_out;
    const int N = in_sizes[0];
    const int nblk = (N + NPB - 1) / NPB;

    sage_kernel<<<nblk, 256, 0, stream>>>(user_nodes, user_nbrs, user_table,
                                          Wsu, bsu, Wnu, bnu, out, N);
    sage_kernel<<<nblk, 256, 0, stream>>>(item_nodes, item_nbrs, item_table,
                                          Wsi, bsi, Wni, bni, out + (size_t)N * DD, N);
}

// Round 2
// 231.861 us; speedup vs baseline: 5.5380x; 5.5380x over previous
//
#include <hip/hip_runtime.h>

#define DD 64          // embedding dim
#define SS 20          // neighbors per node
#define NB 8           // nodes per wave-batch (W-read amortization + reg budget)
#define BATCHES 2      // batches per wave
#define NPW (NB * BATCHES)   // 16 nodes per wave
#define NPB (NPW * 4)        // 64 nodes per block (4 waves)

__device__ __forceinline__ float bcastf(float v, int k) {
    // wave-uniform broadcast of lane k's value -> SGPR (feeds FMA as scalar src)
    return __int_as_float(__builtin_amdgcn_readlane(__float_as_int(v), k));
}

// One fused launch for both sides. Block = 256 threads = 4 waves.
// Phase A: per node, gather self row + mean of 20 neighbor rows (lane = dim).
//          Neighbor indices readlane'd to SGPR -> each row read is one
//          coalesced 256B global_load with SGPR base.
// Phase B: h[j=lane] = bias + sum_k x[k] * W2[j][k], x broadcast via readlane,
//          W transposed + XOR-swizzled in LDS (conflict-free b32, amortized 8x).
// Epilogue: relu -> L2 normalize (shfl_xor reduce) -> coalesced store.
__global__ __launch_bounds__(256, 4) void sage_fused(
    const int*   __restrict__ u_nodes, const int* __restrict__ i_nodes,
    const int*   __restrict__ u_nbrs,  const int* __restrict__ i_nbrs,
    const float* __restrict__ u_table, const float* __restrict__ i_table,
    const float* __restrict__ Wsu, const float* __restrict__ bsu,
    const float* __restrict__ Wnu, const float* __restrict__ bnu,
    const float* __restrict__ Wsi, const float* __restrict__ bsi,
    const float* __restrict__ Wni, const float* __restrict__ bni,
    float* __restrict__ out, int N, int nblk_side)
{
    __shared__ float WTs[64 * 64];   // Ws^T swizzled: [k][j ^ (k&31)]
    __shared__ float WTn[64 * 64];   // Wn^T swizzled

    const int tid  = threadIdx.x;
    const int lane = tid & 63;
    const int wid  = tid >> 6;

    const bool item_side = (int)blockIdx.x >= nblk_side;
    const int  blk = item_side ? (int)blockIdx.x - nblk_side : (int)blockIdx.x;

    const int*   nodes = item_side ? i_nodes : u_nodes;
    const int*   nbrs  = item_side ? i_nbrs  : u_nbrs;
    const float* table = item_side ? i_table : u_table;
    const float* Ws    = item_side ? Wsi : Wsu;
    const float* bsp   = item_side ? bsi : bsu;
    const float* Wn    = item_side ? Wni : Wnu;
    const float* bnp   = item_side ? bni : bnu;
    float* o = out + (item_side ? (size_t)N * DD : 0);

    // --- stage W^T (swizzled) into LDS; conflict-free writes ---
    for (int i = tid; i < 64 * 64; i += 256) {
        const int j  = i >> 6;        // output dim (row of W)
        const int k  = i & 63;        // input dim
        const int jj = j ^ (k & 31);  // swizzle
        WTs[k * 64 + jj] = Ws[i];
        WTn[k * 64 + jj] = Wn[i];
    }
    const float bias = bsp[lane] + bnp[lane];
    __syncthreads();

    const int base = blk * NPB + wid * NPW;

    for (int itb = 0; itb < BATCHES; ++itb) {
        const int n0 = base + itb * NB;

        // ---- Phase A: gather (lane = dim) ----
        float selfv[NB], agg[NB];
        #pragma unroll
        for (int u = 0; u < NB; ++u) {
            selfv[u] = 0.f;
            agg[u]   = 0.f;
            const int ni = n0 + u;
            if (ni < N) {                       // wave-uniform
                const int idx = nodes[ni];
                selfv[u] = table[(size_t)idx * DD + lane];
                int nb = 0;
                if (lane < SS) nb = nbrs[(size_t)ni * SS + lane];
                float a = 0.f;
                #pragma unroll
                for (int s = 0; s < SS; ++s) {
                    const int bi = __builtin_amdgcn_readlane(nb, s);  // -> SGPR base
                    a += table[(size_t)bi * DD + lane];               // coalesced 256B
                }
                agg[u] = a * (1.0f / SS);
            }
        }

        // ---- Phase B: matmul, x broadcast via readlane ----
        float h[NB];
        #pragma unroll
        for (int u = 0; u < NB; ++u) h[u] = bias;

        #pragma unroll 4
        for (int k = 0; k < 64; ++k) {
            const int a = k * 64 + (lane ^ (k & 31));
            const float ws = WTs[a];
            const float wn = WTn[a];
            #pragma unroll
            for (int u = 0; u < NB; ++u) {
                h[u] = fmaf(bcastf(selfv[u], k), ws, h[u]);
                h[u] = fmaf(bcastf(agg[u],  k), wn, h[u]);
            }
        }

        // ---- Epilogue: relu -> L2 normalize -> store ----
        #pragma unroll
        for (int u = 0; u < NB; ++u) {
            const int ni = n0 + u;
            if (ni >= N) continue;              // wave-uniform
            const float v = fmaxf(h[u], 0.f);
            float ss2 = v * v;
            #pragma unroll
            for (int off = 32; off > 0; off >>= 1)
                ss2 += __shfl_xor(ss2, off, 64);
            const float nrm = fmaxf(sqrtf(ss2), 1e-12f);
            o[(size_t)ni * DD + lane] = v / nrm;
        }
    }
}

extern "C" void kernel_launch(void* const* d_in, const int* in_sizes, int n_in,
                              void* d_out, int out_size, void* d_ws, size_t ws_size,
                              hipStream_t stream) {
    const int*   user_nodes = (const int*)  d_in[0];
    const int*   item_nodes = (const int*)  d_in[1];
    const int*   user_nbrs  = (const int*)  d_in[2];
    const int*   item_nbrs  = (const int*)  d_in[3];
    const float* user_table = (const float*)d_in[4];
    const float* item_table = (const float*)d_in[5];
    const float* Wsu = (const float*)d_in[6];
    const float* bsu = (const float*)d_in[7];
    const float* Wnu = (const float*)d_in[8];
    const float* bnu = (const float*)d_in[9];
    const float* Wsi = (const float*)d_in[10];
    const float* bsi = (const float*)d_in[11];
    const float* Wni = (const float*)d_in[12];
    const float* bni = (const float*)d_in[13];

    float* out = (float*)d_out;
    const int N = in_sizes[0];
    const int nblk_side = (N + NPB - 1) / NPB;

    sage_fused<<<2 * nblk_side, 256, 0, stream>>>(
        user_nodes, item_nodes, user_nbrs, item_nbrs,
        user_table, item_table,
        Wsu, bsu, Wnu, bnu, Wsi, bsi, Wni, bni,
        out, N, nblk_side);
}

// Round 3
// 168.369 us; speedup vs baseline: 7.6263x; 1.3771x over previous
//
#include <hip/hip_runtime.h>

typedef __attribute__((ext_vector_type(8))) short bf16x8;
typedef __attribute__((ext_vector_type(4))) float f32x4;

#define DD 64
#define SS 20
#define NPW 16            // nodes per wave = one MFMA M-tile
#define NPB 64            // nodes per block (4 waves)

// swizzle: word index (0..63, 4B units) within a 256B X row; chunk(16B) ^= row&15
#define SWZ(u, w) ((((((w) >> 2)) ^ ((u) & 15)) << 2) | ((w) & 3))

__device__ __forceinline__ unsigned cvt_pk_bf16(float lo, float hi) {
    unsigned r;
    asm("v_cvt_pk_bf16_f32 %0, %1, %2" : "=v"(r) : "v"(lo), "v"(hi));
    return r;
}

// One fused launch, both sides. Block = 256 threads = 4 waves, 64 nodes.
// Phase 0: pack W2^T (=[Ws|Wn] cols) as bf16 MFMA B-fragments in LDS (16 frags).
// Phase A: gather self + mean(20 neighbors), lane = dim; SGPR-base row loads.
// Phase B: pack x->bf16 (shfl+cvt_pk), write swizzled per-wave LDS X tile;
//          4x4 mfma_f32_16x16x32_bf16 -> acc[4] (N=64, K=128, M=16).
// Epilogue: +bias, relu, 16-lane-group norm reduce, guarded stores.
__global__ __launch_bounds__(256, 4) void sage_mfma(
    const int*   __restrict__ u_nodes, const int* __restrict__ i_nodes,
    const int*   __restrict__ u_nbrs,  const int* __restrict__ i_nbrs,
    const float* __restrict__ u_table, const float* __restrict__ i_table,
    const float* __restrict__ Wsu, const float* __restrict__ bsu,
    const float* __restrict__ Wnu, const float* __restrict__ bnu,
    const float* __restrict__ Wsi, const float* __restrict__ bsi,
    const float* __restrict__ Wni, const float* __restrict__ bni,
    float* __restrict__ out, int N, int nblk_side)
{
    __shared__ unsigned BP[16 * 64 * 4];   // 16 B-frags x 64 lanes x 16B = 16 KB
    __shared__ unsigned XW[4][NPW][64];    // per-wave bf16 X tile, swizzled: 16 KB

    const int tid  = threadIdx.x;
    const int lane = tid & 63;
    const int wid  = tid >> 6;

    const bool item_side = (int)blockIdx.x >= nblk_side;
    const int  blk = item_side ? (int)blockIdx.x - nblk_side : (int)blockIdx.x;

    const int*   nodes = item_side ? i_nodes : u_nodes;
    const int*   nbrs  = item_side ? i_nbrs  : u_nbrs;
    const float* table = item_side ? i_table : u_table;
    const float* Ws    = item_side ? Wsi : Wsu;
    const float* bsp   = item_side ? bsi : bsu;
    const float* Wn    = item_side ? Wni : Wnu;
    const float* bnp   = item_side ? bni : bnu;
    float* o = out + (item_side ? (size_t)N * DD : 0);

    // ---- Phase 0: W2^T -> bf16 B-fragments in LDS ----
    // frag(t,c): lane l holds B[k = t*32 + (l>>4)*8 + i][n = c*16 + (l&15)],
    // i=0..7, B[k][n] = W2[n][k] (Ws for k<64, Wn for k>=64).
    #pragma unroll
    for (int it = 0; it < 4; ++it) {
        const int fid = it * 4 + wid;          // 0..15, wave-uniform
        const int t = fid >> 2, c = fid & 3;
        const int n  = c * 16 + (lane & 15);
        const int kb = t * 32 + ((lane >> 4) << 3);
        const float* src = (kb < 64) ? (Ws + n * 64 + kb) : (Wn + n * 64 + (kb - 64));
        const float4 v0 = *(const float4*)(src);
        const float4 v1 = *(const float4*)(src + 4);
        uint4 p;
        p.x = cvt_pk_bf16(v0.x, v0.y);
        p.y = cvt_pk_bf16(v0.z, v0.w);
        p.z = cvt_pk_bf16(v1.x, v1.y);
        p.w = cvt_pk_bf16(v1.z, v1.w);
        *(uint4*)&BP[(fid * 64 + lane) * 4] = p;
    }

    float bcol[4];
    #pragma unroll
    for (int c = 0; c < 4; ++c) {
        const int col = c * 16 + (lane & 15);
        bcol[c] = bsp[col] + bnp[col];
    }
    __syncthreads();

    const int n0 = blk * NPB + wid * NPW;

    // ---- Phase A+B: gather 16 nodes (two halves of 8), pack into X tile ----
    #pragma unroll
    for (int half = 0; half < 2; ++half) {
        float sv[8], ag[8];
        #pragma unroll
        for (int v = 0; v < 8; ++v) {
            const int u  = half * 8 + v;
            const int ni = n0 + u;
            sv[v] = 0.f; ag[v] = 0.f;
            if (ni < N) {                              // wave-uniform
                const int idx = nodes[ni];
                sv[v] = table[(size_t)idx * DD + lane];
                int nb = 0;
                if (lane < SS) nb = nbrs[(size_t)ni * SS + lane];
                float a = 0.f;
                #pragma unroll
                for (int s = 0; s < SS; ++s) {
                    const int bi = __builtin_amdgcn_readlane(nb, s); // SGPR base
                    a += table[(size_t)bi * DD + lane];              // 256B row
                }
                ag[v] = a * (1.0f / SS);
            }
        }
        #pragma unroll
        for (int v = 0; v < 8; ++v) {
            const int u  = half * 8 + v;
            const float s1 = __shfl_xor(sv[v], 1, 64);
            const float a1 = __shfl_xor(ag[v], 1, 64);
            const unsigned ps = cvt_pk_bf16(sv[v], s1);  // (x_l, x_{l+1})
            const unsigned pa = cvt_pk_bf16(ag[v], a1);
            if ((lane & 1) == 0) {
                const int w = lane >> 1;                 // word 0..31
                XW[wid][u][SWZ(u, w)]      = ps;         // self: k 0..63
                XW[wid][u][SWZ(u, 32 + w)] = pa;         // agg:  k 64..127
            }
        }
    }
    // X written & read by same wave: compiler inserts lgkmcnt for the
    // __shared__ dependence; no block barrier needed (per-wave tile).

    // ---- MFMA: M=16, N=64, K=128 ----
    union AB { uint4 u4; bf16x8 v; };
    const f32x4 zero = {0.f, 0.f, 0.f, 0.f};
    f32x4 acc[4] = {zero, zero, zero, zero};
    #pragma unroll
    for (int t = 0; t < 4; ++t) {
        const int r     = lane & 15;
        const int chunk = t * 4 + (lane >> 4);           // k = chunk*8
        AB a;
        a.u4 = *(const uint4*)&XW[wid][r][((chunk ^ r) << 2)];
        #pragma unroll
        for (int c = 0; c < 4; ++c) {
            AB b;
            b.u4 = *(const uint4*)&BP[((t * 4 + c) * 64 + lane) * 4];
            acc[c] = __builtin_amdgcn_mfma_f32_16x16x32_bf16(a.v, b.v, acc[c], 0, 0, 0);
        }
    }

    // ---- Epilogue: bias, relu, row-norm (16-lane-group reduce), store ----
    float rl[4][4];
    float ssq[4] = {0.f, 0.f, 0.f, 0.f};
    #pragma unroll
    for (int c = 0; c < 4; ++c) {
        #pragma unroll
        for (int j = 0; j < 4; ++j) {
            const float v = fmaxf(acc[c][j] + bcol[c], 0.f);
            rl[c][j] = v;
            ssq[j] = fmaf(v, v, ssq[j]);
        }
    }
    #pragma unroll
    for (int j = 0; j < 4; ++j) {
        #pragma unroll
        for (int m = 1; m < 16; m <<= 1)
            ssq[j] += __shfl_xor(ssq[j], m, 64);
    }
    float inv[4];
    #pragma unroll
    for (int j = 0; j < 4; ++j)
        inv[j] = 1.0f / fmaxf(sqrtf(ssq[j]), 1e-12f);

    #pragma unroll
    for (int j = 0; j < 4; ++j) {
        const int row = ((lane >> 4) << 2) + j;          // C/D: row=(l>>4)*4+reg
        const int ni  = n0 + row;
        if (ni < N) {
            #pragma unroll
            for (int c = 0; c < 4; ++c)
                o[(size_t)ni * DD + c * 16 + (lane & 15)] = rl[c][j] * inv[j];
        }
    }
}

extern "C" void kernel_launch(void* const* d_in, const int* in_sizes, int n_in,
                              void* d_out, int out_size, void* d_ws, size_t ws_size,
                              hipStream_t stream) {
    const int*   user_nodes = (const int*)  d_in[0];
    const int*   item_nodes = (const int*)  d_in[1];
    const int*   user_nbrs  = (const int*)  d_in[2];
    const int*   item_nbrs  = (const int*)  d_in[3];
    const float* user_table = (const float*)d_in[4];
    const float* item_table = (const float*)d_in[5];
    const float* Wsu = (const float*)d_in[6];
    const float* bsu = (const float*)d_in[7];
    const float* Wnu = (const float*)d_in[8];
    const float* bnu = (const float*)d_in[9];
    const float* Wsi = (const float*)d_in[10];
    const float* bsi = (const float*)d_in[11];
    const float* Wni = (const float*)d_in[12];
    const float* bni = (const float*)d_in[13];

    float* out = (float*)d_out;
    const int N = in_sizes[0];
    const int nblk_side = (N + NPB - 1) / NPB;

    sage_mfma<<<2 * nblk_side, 256, 0, stream>>>(
        user_nodes, item_nodes, user_nbrs, item_nbrs,
        user_table, item_table,
        Wsu, bsu, Wnu, bnu, Wsi, bsi, Wni, bni,
        out, N, nblk_side);
}

// Round 4
// 155.066 us; speedup vs baseline: 8.2806x; 1.0858x over previous
//
#include <hip/hip_runtime.h>

typedef __attribute__((ext_vector_type(8))) short bf16x8;
typedef __attribute__((ext_vector_type(4))) float f32x4;

#define DD 64
#define SS 20
#define NPW 16            // nodes per wave = one MFMA M-tile
#define NPB 64            // nodes per block (4 waves)

// swizzle: word index (0..63, 4B units) within a 256B X row; chunk(16B) ^= row&15
#define SWZ(u, w) ((((((w) >> 2)) ^ ((u) & 15)) << 2) | ((w) & 3))

__device__ __forceinline__ unsigned cvt_pk_bf16(float lo, float hi) {
    unsigned r;
    asm("v_cvt_pk_bf16_f32 %0, %1, %2" : "=v"(r) : "v"(lo), "v"(hi));
    return r;
}

// Block = 256 threads = 4 waves, 64 nodes; one fused launch, both sides.
// Gather: 4-node sub-batches; 16-lane group g owns node u0+g. Each
// global_load_dwordx4 (16B/lane, 1KB/wave) fetches one 256B table row for
// each of the 4 groups' nodes -> 21 loads per 4 nodes (vs 84 scalar-row
// loads), 4x deeper memory-level parallelism per vmcnt slot.
__global__ __launch_bounds__(256, 4) void sage_mfma(
    const int*   __restrict__ u_nodes, const int* __restrict__ i_nodes,
    const int*   __restrict__ u_nbrs,  const int* __restrict__ i_nbrs,
    const float* __restrict__ u_table, const float* __restrict__ i_table,
    const float* __restrict__ Wsu, const float* __restrict__ bsu,
    const float* __restrict__ Wnu, const float* __restrict__ bnu,
    const float* __restrict__ Wsi, const float* __restrict__ bsi,
    const float* __restrict__ Wni, const float* __restrict__ bni,
    float* __restrict__ out, int N, int nblk_side)
{
    __shared__ unsigned BP[16 * 64 * 4];   // 16 B-frags x 64 lanes x 16B = 16 KB
    __shared__ unsigned XW[4][NPW][64];    // per-wave bf16 X tile, swizzled: 16 KB

    const int tid    = threadIdx.x;
    const int lane   = tid & 63;
    const int wid    = tid >> 6;
    const int lane15 = lane & 15;
    const int grp    = lane >> 4;

    const bool item_side = (int)blockIdx.x >= nblk_side;
    const int  blk = item_side ? (int)blockIdx.x - nblk_side : (int)blockIdx.x;

    const int*   nodes = item_side ? i_nodes : u_nodes;
    const int*   nbrs  = item_side ? i_nbrs  : u_nbrs;
    const float* table = item_side ? i_table : u_table;
    const float* Ws    = item_side ? Wsi : Wsu;
    const float* bsp   = item_side ? bsi : bsu;
    const float* Wn    = item_side ? Wni : Wnu;
    const float* bnp   = item_side ? bni : bnu;
    float* o = out + (item_side ? (size_t)N * DD : 0);

    // ---- Phase 0: W2^T -> bf16 B-fragments in LDS ----
    // frag(t,c): lane l holds B[k = t*32 + (l>>4)*8 + i][n = c*16 + (l&15)],
    // B[k][n] = W2[n][k] (Ws for k<64, Wn for k>=64).
    #pragma unroll
    for (int it = 0; it < 4; ++it) {
        const int fid = it * 4 + wid;          // 0..15, wave-uniform
        const int t = fid >> 2, c = fid & 3;
        const int n  = c * 16 + lane15;
        const int kb = t * 32 + ((lane >> 4) << 3);
        const float* src = (kb < 64) ? (Ws + n * 64 + kb) : (Wn + n * 64 + (kb - 64));
        const float4 v0 = *(const float4*)(src);
        const float4 v1 = *(const float4*)(src + 4);
        uint4 p;
        p.x = cvt_pk_bf16(v0.x, v0.y);
        p.y = cvt_pk_bf16(v0.z, v0.w);
        p.z = cvt_pk_bf16(v1.x, v1.y);
        p.w = cvt_pk_bf16(v1.z, v1.w);
        *(uint4*)&BP[(fid * 64 + lane) * 4] = p;
    }

    float bcol[4];
    #pragma unroll
    for (int c = 0; c < 4; ++c) {
        const int col = c * 16 + lane15;
        bcol[c] = bsp[col] + bnp[col];
    }
    __syncthreads();

    const int n0 = blk * NPB + wid * NPW;
    if (n0 >= N) return;   // whole-wave tail guard (no barriers below)

    // self indices for this wave's 16 nodes, staged in lanes 0..15
    const int nd = nodes[min(n0 + lane15, N - 1)];

    // ---- gather 16 nodes in 4 sub-batches of 4 ----
    #pragma unroll
    for (int sb = 0; sb < 4; ++sb) {
        const int u  = sb * 4 + grp;                 // node owned by this group
        const int nn = min(n0 + u, N - 1);

        // neighbor indices of node nn staged across this group's 16 lanes
        const int  nb0 = nbrs[(size_t)nn * SS + lane15];                       // s=0..15
        const long f1  = min((long)nn * SS + 16 + lane15, (long)N * SS - 1);
        const int  nb1 = nbrs[f1];                                             // s=16..19 (lane15<4)

        // self row (1 dwordx4: 4 rows, one per group)
        const int sidx = __shfl(nd, u, 64);
        const float4 self4 = ((const float4*)(table + (size_t)sidx * DD))[lane15];

        float4 agg = {0.f, 0.f, 0.f, 0.f};
        #pragma unroll
        for (int b = 0; b < SS; ++b) {
            const int idx = (b < 16) ? __shfl(nb0, (lane & 48) | b, 64)
                                     : __shfl(nb1, (lane & 48) | (b - 16), 64);
            const float4 r4 = ((const float4*)(table + (size_t)idx * DD))[lane15];
            agg.x += r4.x; agg.y += r4.y; agg.z += r4.z; agg.w += r4.w;
        }
        const float is = 1.0f / SS;

        // pack to bf16 and write swizzled XW row u (lane m holds dims 4m..4m+3)
        const int m = lane15;
        uint2 pself, pagg;
        pself.x = cvt_pk_bf16(self4.x, self4.y);
        pself.y = cvt_pk_bf16(self4.z, self4.w);
        pagg.x  = cvt_pk_bf16(agg.x * is, agg.y * is);
        pagg.y  = cvt_pk_bf16(agg.z * is, agg.w * is);
        *(uint2*)&XW[wid][u][SWZ(u, 2 * m)]      = pself;   // k = 4m..4m+3
        *(uint2*)&XW[wid][u][SWZ(u, 32 + 2 * m)] = pagg;    // k = 64+4m..
    }
    // XW written & read by the same wave -> lgkmcnt dependence, no barrier.

    // ---- MFMA: M=16, N=64, K=128 ----
    union AB { uint4 u4; bf16x8 v; };
    const f32x4 zero = {0.f, 0.f, 0.f, 0.f};
    f32x4 acc[4] = {zero, zero, zero, zero};
    #pragma unroll
    for (int t = 0; t < 4; ++t) {
        const int r     = lane15;
        const int chunk = t * 4 + grp;               // k = chunk*8
        AB a;
        a.u4 = *(const uint4*)&XW[wid][r][((chunk ^ r) << 2)];
        #pragma unroll
        for (int c = 0; c < 4; ++c) {
            AB b;
            b.u4 = *(const uint4*)&BP[((t * 4 + c) * 64 + lane) * 4];
            acc[c] = __builtin_amdgcn_mfma_f32_16x16x32_bf16(a.v, b.v, acc[c], 0, 0, 0);
        }
    }

    // ---- Epilogue: bias, relu, row-norm (16-lane-group reduce), store ----
    float rl[4][4];
    float ssq[4] = {0.f, 0.f, 0.f, 0.f};
    #pragma unroll
    for (int c = 0; c < 4; ++c) {
        #pragma unroll
        for (int j = 0; j < 4; ++j) {
            const float v = fmaxf(acc[c][j] + bcol[c], 0.f);
            rl[c][j] = v;
            ssq[j] = fmaf(v, v, ssq[j]);
        }
    }
    #pragma unroll
    for (int j = 0; j < 4; ++j) {
        #pragma unroll
        for (int m = 1; m < 16; m <<= 1)
            ssq[j] += __shfl_xor(ssq[j], m, 64);
    }
    float inv[4];
    #pragma unroll
    for (int j = 0; j < 4; ++j)
        inv[j] = 1.0f / fmaxf(sqrtf(ssq[j]), 1e-12f);

    #pragma unroll
    for (int j = 0; j < 4; ++j) {
        const int row = (grp << 2) + j;              // C/D: row=(l>>4)*4+reg
        const int ni  = n0 + row;
        if (ni < N) {
            #pragma unroll
            for (int c = 0; c < 4; ++c)
                o[(size_t)ni * DD + c * 16 + lane15] = rl[c][j] * inv[j];
        }
    }
}

extern "C" void kernel_launch(void* const* d_in, const int* in_sizes, int n_in,
                              void* d_out, int out_size, void* d_ws, size_t ws_size,
                              hipStream_t stream) {
    const int*   user_nodes = (const int*)  d_in[0];
    const int*   item_nodes = (const int*)  d_in[1];
    const int*   user_nbrs  = (const int*)  d_in[2];
    const int*   item_nbrs  = (const int*)  d_in[3];
    const float* user_table = (const float*)d_in[4];
    const float* item_table = (const float*)d_in[5];
    const float* Wsu = (const float*)d_in[6];
    const float* bsu = (const float*)d_in[7];
    const float* Wnu = (const float*)d_in[8];
    const float* bnu = (const float*)d_in[9];
    const float* Wsi = (const float*)d_in[10];
    const float* bsi = (const float*)d_in[11];
    const float* Wni = (const float*)d_in[12];
    const float* bni = (const float*)d_in[13];

    float* out = (float*)d_out;
    const int N = in_sizes[0];
    const int nblk_side = (N + NPB - 1) / NPB;

    sage_mfma<<<2 * nblk_side, 256, 0, stream>>>(
        user_nodes, item_nodes, user_nbrs, item_nbrs,
        user_table, item_table,
        Wsu, bsu, Wnu, bnu, Wsi, bsi, Wni, bni,
        out, N, nblk_side);
}